// Round 5
// baseline (7462.143 us; speedup 1.0000x reference)
//
#include <hip/hip_runtime.h>
#include <stdint.h>

typedef unsigned short u16;
typedef __bf16 bf16x8 __attribute__((ext_vector_type(8)));
typedef float f32x4 __attribute__((ext_vector_type(4)));

#define MT 16384   // BATCH*SEQ tokens

__device__ __forceinline__ u16 f2bf(float f) {
  union { float f; unsigned u; } x; x.f = f;
  unsigned r = x.u + 0x7fffu + ((x.u >> 16) & 1u);   // RNE
  return (u16)(r >> 16);
}

#pragma clang diagnostic push
#pragma clang diagnostic ignored "-Waddress-space-conversion"
typedef __attribute__((address_space(1))) unsigned as1u;
typedef __attribute__((address_space(3))) unsigned as3u;
// async global->LDS, 16B per lane; lbase must be wave-uniform (HW adds lane*16)
__device__ __forceinline__ void stage16(const u16* g, u16* lbase) {
  __builtin_amdgcn_global_load_lds((as1u*)g, (as3u*)lbase, 16, 0, 0);
}
#pragma clang diagnostic pop

// ---------------- weight transpose + f32->bf16 convert ----------------
__global__ void __launch_bounds__(256)
transpose_cvt(const float* __restrict__ in, u16* __restrict__ out, int K, int N) {
  __shared__ float tile[32][33];
  const int k0 = blockIdx.y * 32, n0 = blockIdx.x * 32;
  const int tx = threadIdx.x, ty = threadIdx.y;   // block (32,8)
  #pragma unroll
  for (int r = 0; r < 32; r += 8)
    tile[ty + r][tx] = in[(size_t)(k0 + ty + r) * N + n0 + tx];
  __syncthreads();
  #pragma unroll
  for (int r = 0; r < 32; r += 8)
    out[(size_t)(n0 + ty + r) * K + k0 + tx] = f2bf(tile[tx][ty + r]);
}

// ---------------- embedding: x = tok_emb[idx] + pos_emb ----------------
__global__ void __launch_bounds__(256)
embed_kernel(const int* __restrict__ idx, const float* __restrict__ tok,
             const float* __restrict__ pos, float* __restrict__ x,
             u16* __restrict__ xb) {
  const int tk = blockIdx.x;
  const int s = tk & 63;
  const int id = idx[tk];
  const int t = threadIdx.x;
  float4 a = ((const float4*)(tok + (size_t)id * 1024))[t];
  float4 p = ((const float4*)(pos + (size_t)s * 1024))[t];
  float4 r; r.x = a.x + p.x; r.y = a.y + p.y; r.z = a.z + p.z; r.w = a.w + p.w;
  ((float4*)(x + (size_t)tk * 1024))[t] = r;
  u16* o = xb + (size_t)tk * 1024 + t * 4;
  o[0] = f2bf(r.x); o[1] = f2bf(r.y); o[2] = f2bf(r.z); o[3] = f2bf(r.w);
}

// ---------------- 128x256 GEMM: C = A[M][K](bf16) @ Bt[N][K]^T + bias ----------------
// 4 waves (1Mx4N), BK=32, 48 KiB double-buffered LDS -> 3 blocks/CU for
// cross-block latency hiding (m114). Row-pair-packed XOR-swizzled LDS layout:
//   phys_granule(row,fg) = (row>>1)*8 + (row&1)*4 + (fg ^ ((row>>1)&3))
// (inverse permutation applied to global_load_lds SOURCE; dest stays linear).
// EPI 0: out bf16 | 1: gelu->bf16 | 2: +res(f32), write f32+bf16 | 3: out f32
template<int EPI>
__global__ void __launch_bounds__(256, 3)
gemm128x256(const u16* __restrict__ A, const u16* __restrict__ Bt,
            const float* __restrict__ bias, float* __restrict__ resf,
            u16* __restrict__ outb, float* __restrict__ outf,
            int M, int N, int K, int gn) {
  __shared__ __align__(16) u16 lA[2][4096];   // 128 x 32 bf16
  __shared__ __align__(16) u16 lB[2][8192];   // 256 x 32 bf16
  const int t = threadIdx.x;
  const int lane = t & 63, w = t >> 6;       // 4 waves, wave w owns cols [w*64,+64)
  const int fr = lane & 15, fg = lane >> 4;

  // XCD swizzle (grid %8==0) + tn-fastest decomposition for A-panel L2 reuse
  const int nwg = gridDim.x;
  const int bid = blockIdx.x;
  const int s = (bid & 7) * (nwg >> 3) + (bid >> 3);
  const int tn = s % gn, tm = s / gn;
  const int m0 = tm * 128, n0 = tn * 256;

  // staging source mapping (inverse of the packed-pair swizzle)
  const int rin = ((lane >> 3) << 1) + ((lane >> 2) & 1);   // row within 16-row chunk
  const int fgl = (lane & 3) ^ ((lane >> 3) & 3);           // logical k-granule
  const u16* gA[2]; const u16* gB[4];
  #pragma unroll
  for (int i = 0; i < 2; ++i)
    gA[i] = A + (size_t)(m0 + (w * 2 + i) * 16 + rin) * K + fgl * 8;
  #pragma unroll
  for (int j = 0; j < 4; ++j)
    gB[j] = Bt + (size_t)(n0 + (w * 4 + j) * 16 + rin) * K + fgl * 8;

  // LDS read offsets (u16 units): line*64 + sub*8
  const int sub8 = ((fr & 1) * 4 + (fg ^ ((fr >> 1) & 3))) * 8;
  const int ar = (fr >> 1) * 64 + sub8;                // + m*512
  const int br = (w * 32 + (fr >> 1)) * 64 + sub8;     // + n*512

  f32x4 acc[8][4] = {};
  const int NT = K >> 5;

  // prologue: tile 0 -> buf 0
  #pragma unroll
  for (int i = 0; i < 2; ++i) stage16(gA[i], &lA[0][(w * 2 + i) * 512]);
  #pragma unroll
  for (int j = 0; j < 4; ++j) stage16(gB[j], &lB[0][(w * 4 + j) * 512]);
  __syncthreads();

  int cur = 0;
  for (int kt = 0; kt < NT; ++kt) {
    if (kt + 1 < NT) {
      const int ko = (kt + 1) << 5;
      #pragma unroll
      for (int i = 0; i < 2; ++i) stage16(gA[i] + ko, &lA[cur ^ 1][(w * 2 + i) * 512]);
      #pragma unroll
      for (int j = 0; j < 4; ++j) stage16(gB[j] + ko, &lB[cur ^ 1][(w * 4 + j) * 512]);
    }
    bf16x8 af[8], bv[4];
    #pragma unroll
    for (int m = 0; m < 8; ++m) af[m] = *(const bf16x8*)&lA[cur][m * 512 + ar];
    #pragma unroll
    for (int n = 0; n < 4; ++n) bv[n] = *(const bf16x8*)&lB[cur][n * 512 + br];
    #pragma unroll
    for (int m = 0; m < 8; ++m)
      #pragma unroll
      for (int n = 0; n < 4; ++n)
        acc[m][n] = __builtin_amdgcn_mfma_f32_16x16x32_bf16(af[m], bv[n], acc[m][n], 0, 0, 0);
    __syncthreads();
    cur ^= 1;
  }

  #pragma unroll
  for (int m = 0; m < 8; ++m) {
    const int row = m0 + m * 16 + fg * 4;
    #pragma unroll
    for (int n = 0; n < 4; ++n) {
      const int col = n0 + w * 64 + n * 16 + fr;
      const float bc = bias[col];
      #pragma unroll
      for (int i = 0; i < 4; ++i) {
        const size_t off = (size_t)(row + i) * N + col;
        float v = acc[m][n][i] + bc;
        if constexpr (EPI == 0) {
          outb[off] = f2bf(v);
        } else if constexpr (EPI == 1) {
          v = 0.5f * v * (1.0f + erff(v * 0.70710678118654752f));
          outb[off] = f2bf(v);
        } else if constexpr (EPI == 2) {
          v += resf[off];
          resf[off] = v;
          outb[off] = f2bf(v);
        } else {
          outf[off] = v;
        }
      }
    }
  }
}

// ---------------- attention (one block per (b,h)) ----------------
__global__ void __launch_bounds__(256)
attn_kernel(const u16* __restrict__ qkv, u16* __restrict__ y) {
  __shared__ __align__(16) u16 qs[64][72];    // Q; reused as P (bf16)
  __shared__ __align__(16) u16 ks[64][72];
  __shared__ __align__(16) u16 vts[64][72];   // V transposed: [dh][key]
  __shared__ __align__(16) float S[64][68];   // [query][key] f32
  __shared__ float red[4][64];

  const int h = blockIdx.x, b = blockIdx.y;
  const int t = threadIdx.x;
  const int lane = t & 63, w = t >> 6;
  const int fr = lane & 15, fg = lane >> 4;

  #pragma unroll
  for (int it = 0; it < 2; ++it) {
    const int id = t + it * 256;           // 0..511
    const int row = id >> 3, seg = id & 7;
    const size_t gq = (size_t)(b * 64 + row) * 3072 + h * 64 + seg * 8;
    *(uint4*)&qs[row][seg * 8] = *(const uint4*)&qkv[gq];
    *(uint4*)&ks[row][seg * 8] = *(const uint4*)&qkv[gq + 1024];
  }
  {
    const int d = t & 63;
    #pragma unroll
    for (int it = 0; it < 16; ++it) {
      const int s = (t >> 6) + it * 4;
      vts[d][s] = qkv[(size_t)(b * 64 + s) * 3072 + 2048 + h * 64 + d];
    }
  }
  __syncthreads();

  f32x4 sa[4] = {};
  #pragma unroll
  for (int kk = 0; kk < 64; kk += 32) {
    bf16x8 qa = *(const bf16x8*)&qs[w * 16 + fr][kk + fg * 8];
    #pragma unroll
    for (int n = 0; n < 4; ++n) {
      bf16x8 kb = *(const bf16x8*)&ks[n * 16 + fr][kk + fg * 8];
      sa[n] = __builtin_amdgcn_mfma_f32_16x16x32_bf16(qa, kb, sa[n], 0, 0, 0);
    }
  }
  #pragma unroll
  for (int n = 0; n < 4; ++n)
    #pragma unroll
    for (int i = 0; i < 4; ++i) {
      const int row = w * 16 + fg * 4 + i, col = n * 16 + fr;
      S[row][col] = (row >= col) ? sa[n][i] * 0.03125f : -1e30f;
    }
  __syncthreads();

  const int c = t & 63, q4 = t >> 6;
  float mx = -1e30f;
  float e[16];
  #pragma unroll
  for (int i = 0; i < 16; ++i) mx = fmaxf(mx, S[q4 * 16 + i][c]);
  red[q4][c] = mx;
  __syncthreads();
  mx = fmaxf(fmaxf(red[0][c], red[1][c]), fmaxf(red[2][c], red[3][c]));
  float sum = 0.f;
  #pragma unroll
  for (int i = 0; i < 16; ++i) { e[i] = __expf(S[q4 * 16 + i][c] - mx); sum += e[i]; }
  __syncthreads();
  red[q4][c] = sum;
  __syncthreads();
  sum = red[0][c] + red[1][c] + red[2][c] + red[3][c];
  const float inv = 1.0f / sum;
  u16 (*P)[72] = qs;
  #pragma unroll
  for (int i = 0; i < 16; ++i)
    P[q4 * 16 + i][c] = f2bf(e[i] * inv);
  __syncthreads();

  f32x4 oa[4] = {};
  #pragma unroll
  for (int kk = 0; kk < 64; kk += 32) {
    bf16x8 pa = *(const bf16x8*)&P[w * 16 + fr][kk + fg * 8];
    #pragma unroll
    for (int n = 0; n < 4; ++n) {
      bf16x8 vb = *(const bf16x8*)&vts[n * 16 + fr][kk + fg * 8];
      oa[n] = __builtin_amdgcn_mfma_f32_16x16x32_bf16(pa, vb, oa[n], 0, 0, 0);
    }
  }
  #pragma unroll
  for (int n = 0; n < 4; ++n)
    #pragma unroll
    for (int i = 0; i < 4; ++i) {
      const int row = w * 16 + fg * 4 + i, col = n * 16 + fr;
      y[(size_t)(b * 64 + row) * 1024 + h * 64 + col] = f2bf(oa[n][i]);
    }
}

// ---------------- final LayerNorm ----------------
__global__ void __launch_bounds__(256)
ln_kernel(const float* __restrict__ x, const float* __restrict__ g,
          const float* __restrict__ bb, u16* __restrict__ xn) {
  __shared__ float sred[8];
  const int tok = blockIdx.x;
  const int t = threadIdx.x;
  const float4 v = ((const float4*)(x + (size_t)tok * 1024))[t];
  float s  = v.x + v.y + v.z + v.w;
  float ss = v.x * v.x + v.y * v.y + v.z * v.z + v.w * v.w;
  #pragma unroll
  for (int o = 32; o > 0; o >>= 1) {
    s  += __shfl_xor(s, o);
    ss += __shfl_xor(ss, o);
  }
  const int w = t >> 6;
  if ((t & 63) == 0) { sred[w] = s; sred[4 + w] = ss; }
  __syncthreads();
  s  = sred[0] + sred[1] + sred[2] + sred[3];
  ss = sred[4] + sred[5] + sred[6] + sred[7];
  const float mu = s * (1.0f / 1024.0f);
  const float var = ss * (1.0f / 1024.0f) - mu * mu;
  const float rs = rsqrtf(var + 1e-5f);
  const float4 gg = ((const float4*)g)[t];
  const float4 b4 = ((const float4*)bb)[t];
  u16* o = xn + (size_t)tok * 1024 + t * 4;
  o[0] = f2bf((v.x - mu) * rs * gg.x + b4.x);
  o[1] = f2bf((v.y - mu) * rs * gg.y + b4.y);
  o[2] = f2bf((v.z - mu) * rs * gg.z + b4.z);
  o[3] = f2bf((v.w - mu) * rs * gg.w + b4.w);
}

// ---------------- host ----------------
extern "C" void kernel_launch(void* const* d_in, const int* in_sizes, int n_in,
                              void* d_out, int out_size, void* d_ws, size_t ws_size,
                              hipStream_t stream) {
  const int*   idx     = (const int*)  d_in[0];
  const float* tok_emb = (const float*)d_in[1];
  const float* pos_emb = (const float*)d_in[2];
  const float* wqkv    = (const float*)d_in[3];
  const float* bqkv    = (const float*)d_in[4];
  const float* wo      = (const float*)d_in[5];
  const float* bo      = (const float*)d_in[6];
  const float* w1      = (const float*)d_in[7];
  const float* b1      = (const float*)d_in[8];
  const float* w2      = (const float*)d_in[9];
  const float* b2      = (const float*)d_in[10];
  const float* ln_g    = (const float*)d_in[11];
  const float* ln_b    = (const float*)d_in[12];
  const float* out_w   = (const float*)d_in[13];
  const float* out_b   = (const float*)d_in[14];

  char* p = (char*)d_ws;
  auto take = [&](size_t n) { char* r = p; p += (n + 255) & ~(size_t)255; return r; };
  u16*   wqkv_t = (u16*)  take((size_t)1024 * 3072 * 2);
  u16*   wo_t   = (u16*)  take((size_t)1024 * 1024 * 2);
  u16*   w1_t   = (u16*)  take((size_t)1024 * 4096 * 2);
  u16*   w2_t   = (u16*)  take((size_t)4096 * 1024 * 2);
  u16*   wout_t = (u16*)  take((size_t)1024 * 1024 * 2);
  float* xf     = (float*)take((size_t)MT * 1024 * 4);
  u16*   xb     = (u16*)  take((size_t)MT * 1024 * 2);
  u16*   yb     = (u16*)  take((size_t)MT * 1024 * 2);
  u16*   big    = (u16*)  take((size_t)MT * 4096 * 2);

  const dim3 tb(32, 8);
  embed_kernel<<<MT, 256, 0, stream>>>(idx, tok_emb, pos_emb, xf, xb);

  for (int l = 0; l < 12; ++l) {
    transpose_cvt<<<dim3(3072 / 32, 1024 / 32), tb, 0, stream>>>(
        wqkv + (size_t)l * 1024 * 3072, wqkv_t, 1024, 3072);
    transpose_cvt<<<dim3(1024 / 32, 1024 / 32), tb, 0, stream>>>(
        wo + (size_t)l * 1024 * 1024, wo_t, 1024, 1024);
    transpose_cvt<<<dim3(4096 / 32, 1024 / 32), tb, 0, stream>>>(
        w1 + (size_t)l * 1024 * 4096, w1_t, 1024, 4096);
    transpose_cvt<<<dim3(1024 / 32, 4096 / 32), tb, 0, stream>>>(
        w2 + (size_t)l * 4096 * 1024, w2_t, 4096, 1024);

    gemm128x256<0><<<(MT / 128) * (3072 / 256), 256, 0, stream>>>(
        xb, wqkv_t, bqkv + (size_t)l * 3072,
        nullptr, big, nullptr, MT, 3072, 1024, 3072 / 256);
    attn_kernel<<<dim3(16, 256), 256, 0, stream>>>(big, yb);
    gemm128x256<2><<<(MT / 128) * (1024 / 256), 256, 0, stream>>>(
        yb, wo_t, bo + (size_t)l * 1024,
        xf, xb, nullptr, MT, 1024, 1024, 1024 / 256);
    gemm128x256<1><<<(MT / 128) * (4096 / 256), 256, 0, stream>>>(
        xb, w1_t, b1 + (size_t)l * 4096,
        nullptr, big, nullptr, MT, 4096, 1024, 4096 / 256);
    gemm128x256<2><<<(MT / 128) * (1024 / 256), 256, 0, stream>>>(
        big, w2_t, b2 + (size_t)l * 1024,
        xf, xb, nullptr, MT, 1024, 4096, 1024 / 256);
  }

  transpose_cvt<<<dim3(1024 / 32, 1024 / 32), tb, 0, stream>>>(out_w, wout_t, 1024, 1024);
  ln_kernel<<<MT, 256, 0, stream>>>(xf, ln_g, ln_b, yb);
  gemm128x256<3><<<(MT / 128) * (1024 / 256), 256, 0, stream>>>(
      yb, wout_t, out_b, nullptr, nullptr, (float*)d_out, MT, 1024, 1024, 1024 / 256);
}

// Round 6
// 7261.089 us; speedup vs baseline: 1.0277x; 1.0277x over previous
//
#include <hip/hip_runtime.h>
#include <stdint.h>

typedef unsigned short u16;
typedef __bf16 bf16x8 __attribute__((ext_vector_type(8)));
typedef float f32x4 __attribute__((ext_vector_type(4)));

#define MT 16384   // BATCH*SEQ tokens

__device__ __forceinline__ u16 f2bf(float f) {
  union { float f; unsigned u; } x; x.f = f;
  unsigned r = x.u + 0x7fffu + ((x.u >> 16) & 1u);   // RNE
  return (u16)(r >> 16);
}

#pragma clang diagnostic push
#pragma clang diagnostic ignored "-Waddress-space-conversion"
typedef __attribute__((address_space(1))) unsigned as1u;
typedef __attribute__((address_space(3))) unsigned as3u;
// async global->LDS, 16B per lane; lbase must be wave-uniform (HW adds lane*16)
__device__ __forceinline__ void stage16(const u16* g, const u16* lbase) {
  __builtin_amdgcn_global_load_lds((as1u*)g, (as3u*)lbase, 16, 0, 0);
}
#pragma clang diagnostic pop

// ---------------- weight transpose + f32->bf16 convert ----------------
__global__ void __launch_bounds__(256)
transpose_cvt(const float* __restrict__ in, u16* __restrict__ out, int K, int N) {
  __shared__ float tile[32][33];
  const int k0 = blockIdx.y * 32, n0 = blockIdx.x * 32;
  const int tx = threadIdx.x, ty = threadIdx.y;   // block (32,8)
  #pragma unroll
  for (int r = 0; r < 32; r += 8)
    tile[ty + r][tx] = in[(size_t)(k0 + ty + r) * N + n0 + tx];
  __syncthreads();
  #pragma unroll
  for (int r = 0; r < 32; r += 8)
    out[(size_t)(n0 + ty + r) * K + k0 + tx] = f2bf(tile[tx][ty + r]);
}

// ---------------- embedding: x = tok_emb[idx] + pos_emb ----------------
__global__ void __launch_bounds__(256)
embed_kernel(const int* __restrict__ idx, const float* __restrict__ tok,
             const float* __restrict__ pos, float* __restrict__ x,
             u16* __restrict__ xb) {
  const int tk = blockIdx.x;
  const int s = tk & 63;
  const int id = idx[tk];
  const int t = threadIdx.x;
  float4 a = ((const float4*)(tok + (size_t)id * 1024))[t];
  float4 p = ((const float4*)(pos + (size_t)s * 1024))[t];
  float4 r; r.x = a.x + p.x; r.y = a.y + p.y; r.z = a.z + p.z; r.w = a.w + p.w;
  ((float4*)(x + (size_t)tk * 1024))[t] = r;
  u16* o = xb + (size_t)tk * 1024 + t * 4;
  o[0] = f2bf(r.x); o[1] = f2bf(r.y); o[2] = f2bf(r.z); o[3] = f2bf(r.w);
}

// ------------- 256x256 8-phase GEMM: C = A[M][K](bf16) @ Bt[N][K]^T + bias -------------
// 8 waves (2Mx4N), BK=64 staged as 4 k-half-tiles/tile (A-kh0,B-kh0,A-kh1,B-kh1;
// 16KB each, 2 global_load_lds per wave per half). Per tile: 4 phases
// {ds_read quadrant | stage 1 half | s_barrier | lgkmcnt(0) | setprio1 16xMFMA setprio0 | s_barrier}
// with counted vmcnt(4) ONLY at p1/p3 (T3+T4): loads stay in flight across barriers.
// Invariant: half consumed at phase p staged 4 phases earlier; vmcnt(4) leaves the
// 2 newest halves outstanding -> consumed half drained. LDS row stride 64B -> even
// bank spread, no swizzle. EPI 0: bf16 | 1: gelu->bf16 | 2: +res f32+bf16 | 3: f32
template<int EPI>
__global__ void __launch_bounds__(512, 1)
gemm256p(const u16* __restrict__ A, const u16* __restrict__ Bt,
         const float* __restrict__ bias, float* __restrict__ resf,
         u16* __restrict__ outb, float* __restrict__ outf,
         int M, int N, int K, int gn) {
  __shared__ __align__(16) u16 lds[65536];   // [buf:2][op:2][kh:2][256 rows][32 k]
  const int t = threadIdx.x;
  const int lane = t & 63, w = t >> 6;
  const int wr = w >> 2, wc = w & 3;
  const int fr = lane & 15, fg = lane >> 4;

  // XCD swizzle (grid %8==0) + tn-fastest decomposition for A-panel L2 reuse
  const int nwg = gridDim.x;
  const int bid = blockIdx.x;
  const int sw = (bid & 7) * (nwg >> 3) + (bid >> 3);
  const int tn = sw % gn, tm = sw / gn;
  const int m0 = tm * 256, n0 = tn * 256;

  // staging: issue i of wave w covers rows [(w*2+i)*16, +16) of a half-tile;
  // lane l -> row +(l>>2), 8-u16 granule l&3  (linear, no swizzle)
  const int srow = w * 32 + (lane >> 2);      // (w*2)*16 + ...
  const int scol = (lane & 3) * 8;
  const u16* gA0 = A  + (size_t)(m0 + srow) * K + scol;
  const u16* gA1 = A  + (size_t)(m0 + srow + 16) * K + scol;
  const u16* gB0 = Bt + (size_t)(n0 + srow) * K + scol;
  const u16* gB1 = Bt + (size_t)(n0 + srow + 16) * K + scol;
  const int dA = w * 1024;            // u16 offset within [kh] region
  const int dB = 16384 + w * 1024;

  f32x4 acc[8][4] = {};
  const int NT = K >> 6;

  auto STAGE_A = [&](int b, int kh, int ko) {
    stage16(gA0 + ko + kh * 32, &lds[b * 32768 + kh * 8192 + dA]);
    stage16(gA1 + ko + kh * 32, &lds[b * 32768 + kh * 8192 + dA + 512]);
  };
  auto STAGE_B = [&](int b, int kh, int ko) {
    stage16(gB0 + ko + kh * 32, &lds[b * 32768 + kh * 8192 + dB]);
    stage16(gB1 + ko + kh * 32, &lds[b * 32768 + kh * 8192 + dB + 512]);
  };
  auto LDA4 = [&](bf16x8* af, int mq, int kh, int c) {
    #pragma unroll
    for (int m = 0; m < 4; ++m)
      af[m] = *(const bf16x8*)&lds[c * 32768 + kh * 8192 +
                                   (wr * 128 + (mq * 4 + m) * 16 + fr) * 32 + fg * 8];
  };
  auto LDB4 = [&](bf16x8* bv, int kh, int c) {
    #pragma unroll
    for (int n = 0; n < 4; ++n)
      bv[n] = *(const bf16x8*)&lds[c * 32768 + 16384 + kh * 8192 +
                                   (wc * 64 + n * 16 + fr) * 32 + fg * 8];
  };
  auto MFMA16 = [&](bf16x8* af, bf16x8* bv, int mq) {
    __builtin_amdgcn_s_setprio(1);
    #pragma unroll
    for (int m = 0; m < 4; ++m)
      #pragma unroll
      for (int n = 0; n < 4; ++n)
        acc[mq * 4 + m][n] =
            __builtin_amdgcn_mfma_f32_16x16x32_bf16(af[m], bv[n], acc[mq * 4 + m][n], 0, 0, 0);
    __builtin_amdgcn_s_setprio(0);
  };
  #define BARRIER() __builtin_amdgcn_s_barrier()
  #define LGKM0()  asm volatile("s_waitcnt lgkmcnt(0)" ::: "memory")
  #define VMCNT4() asm volatile("s_waitcnt vmcnt(4)" ::: "memory")

  // prologue: tile 0 -> buf 0 (stream order A0,B0,A1,B1)
  STAGE_A(0, 0, 0); STAGE_B(0, 0, 0);
  STAGE_A(0, 1, 0); STAGE_B(0, 1, 0);
  VMCNT4();                    // kh0 halves landed
  BARRIER();

  int cur = 0;
  for (int u = 0; u < NT; ++u) {
    const int ko = (u + 1 < NT) ? (u + 1) << 6 : 0;   // wrap: keeps vmcnt stream uniform
    const int nb = cur ^ 1;
    bf16x8 bv[4];
    { // p0: quadrant (kh0, m0-3)
      bf16x8 af[4];
      LDA4(af, 0, 0, cur); LDB4(bv, 0, cur);
      STAGE_A(nb, 0, ko);
      BARRIER(); LGKM0();
      MFMA16(af, bv, 0);
      BARRIER();
    }
    { // p1: quadrant (kh0, m4-7)
      bf16x8 af[4];
      LDA4(af, 1, 0, cur);
      STAGE_B(nb, 0, ko);
      VMCNT4();                // guarantees kh1(u) halves (staged 4 phases ago)
      BARRIER(); LGKM0();
      MFMA16(af, bv, 1);
      BARRIER();
    }
    { // p2: quadrant (kh1, m0-3)
      bf16x8 af[4];
      LDA4(af, 0, 1, cur); LDB4(bv, 1, cur);
      STAGE_A(nb, 1, ko);
      BARRIER(); LGKM0();
      MFMA16(af, bv, 0);
      BARRIER();
    }
    { // p3: quadrant (kh1, m4-7)
      bf16x8 af[4];
      LDA4(af, 1, 1, cur);
      STAGE_B(nb, 1, ko);
      VMCNT4();                // guarantees kh0(u+1) halves
      BARRIER(); LGKM0();
      MFMA16(af, bv, 1);
      BARRIER();
    }
    cur = nb;
  }
  #undef BARRIER
  #undef LGKM0
  #undef VMCNT4

  #pragma unroll
  for (int m = 0; m < 8; ++m) {
    const int row = m0 + wr * 128 + m * 16 + fg * 4;
    #pragma unroll
    for (int n = 0; n < 4; ++n) {
      const int col = n0 + wc * 64 + n * 16 + fr;
      const float bc = bias[col];
      #pragma unroll
      for (int i = 0; i < 4; ++i) {
        const size_t off = (size_t)(row + i) * N + col;
        float v = acc[m][n][i] + bc;
        if constexpr (EPI == 0) {
          outb[off] = f2bf(v);
        } else if constexpr (EPI == 1) {
          v = 0.5f * v * (1.0f + erff(v * 0.70710678118654752f));
          outb[off] = f2bf(v);
        } else if constexpr (EPI == 2) {
          v += resf[off];
          resf[off] = v;
          outb[off] = f2bf(v);
        } else {
          outf[off] = v;
        }
      }
    }
  }
}

// ---------------- attention (one block per (b,h)) ----------------
__global__ void __launch_bounds__(256)
attn_kernel(const u16* __restrict__ qkv, u16* __restrict__ y) {
  __shared__ __align__(16) u16 qs[64][72];    // Q; reused as P (bf16)
  __shared__ __align__(16) u16 ks[64][72];
  __shared__ __align__(16) u16 vts[64][72];   // V transposed: [dh][key]
  __shared__ __align__(16) float S[64][68];   // [query][key] f32
  __shared__ float red[4][64];

  const int h = blockIdx.x, b = blockIdx.y;
  const int t = threadIdx.x;
  const int lane = t & 63, w = t >> 6;
  const int fr = lane & 15, fg = lane >> 4;

  #pragma unroll
  for (int it = 0; it < 2; ++it) {
    const int id = t + it * 256;           // 0..511
    const int row = id >> 3, seg = id & 7;
    const size_t gq = (size_t)(b * 64 + row) * 3072 + h * 64 + seg * 8;
    *(uint4*)&qs[row][seg * 8] = *(const uint4*)&qkv[gq];
    *(uint4*)&ks[row][seg * 8] = *(const uint4*)&qkv[gq + 1024];
  }
  {
    const int d = t & 63;
    #pragma unroll
    for (int it = 0; it < 16; ++it) {
      const int s = (t >> 6) + it * 4;
      vts[d][s] = qkv[(size_t)(b * 64 + s) * 3072 + 2048 + h * 64 + d];
    }
  }
  __syncthreads();

  f32x4 sa[4] = {};
  #pragma unroll
  for (int kk = 0; kk < 64; kk += 32) {
    bf16x8 qa = *(const bf16x8*)&qs[w * 16 + fr][kk + fg * 8];
    #pragma unroll
    for (int n = 0; n < 4; ++n) {
      bf16x8 kb = *(const bf16x8*)&ks[n * 16 + fr][kk + fg * 8];
      sa[n] = __builtin_amdgcn_mfma_f32_16x16x32_bf16(qa, kb, sa[n], 0, 0, 0);
    }
  }
  #pragma unroll
  for (int n = 0; n < 4; ++n)
    #pragma unroll
    for (int i = 0; i < 4; ++i) {
      const int row = w * 16 + fg * 4 + i, col = n * 16 + fr;
      S[row][col] = (row >= col) ? sa[n][i] * 0.03125f : -1e30f;
    }
  __syncthreads();

  const int c = t & 63, q4 = t >> 6;
  float mx = -1e30f;
  float e[16];
  #pragma unroll
  for (int i = 0; i < 16; ++i) mx = fmaxf(mx, S[q4 * 16 + i][c]);
  red[q4][c] = mx;
  __syncthreads();
  mx = fmaxf(fmaxf(red[0][c], red[1][c]), fmaxf(red[2][c], red[3][c]));
  float sum = 0.f;
  #pragma unroll
  for (int i = 0; i < 16; ++i) { e[i] = __expf(S[q4 * 16 + i][c] - mx); sum += e[i]; }
  __syncthreads();
  red[q4][c] = sum;
  __syncthreads();
  sum = red[0][c] + red[1][c] + red[2][c] + red[3][c];
  const float inv = 1.0f / sum;
  u16 (*P)[72] = qs;
  #pragma unroll
  for (int i = 0; i < 16; ++i)
    P[q4 * 16 + i][c] = f2bf(e[i] * inv);
  __syncthreads();

  f32x4 oa[4] = {};
  #pragma unroll
  for (int kk = 0; kk < 64; kk += 32) {
    bf16x8 pa = *(const bf16x8*)&P[w * 16 + fr][kk + fg * 8];
    #pragma unroll
    for (int n = 0; n < 4; ++n) {
      bf16x8 vb = *(const bf16x8*)&vts[n * 16 + fr][kk + fg * 8];
      oa[n] = __builtin_amdgcn_mfma_f32_16x16x32_bf16(pa, vb, oa[n], 0, 0, 0);
    }
  }
  #pragma unroll
  for (int n = 0; n < 4; ++n)
    #pragma unroll
    for (int i = 0; i < 4; ++i) {
      const int row = w * 16 + fg * 4 + i, col = n * 16 + fr;
      y[(size_t)(b * 64 + row) * 1024 + h * 64 + col] = f2bf(oa[n][i]);
    }
}

// ---------------- final LayerNorm ----------------
__global__ void __launch_bounds__(256)
ln_kernel(const float* __restrict__ x, const float* __restrict__ g,
          const float* __restrict__ bb, u16* __restrict__ xn) {
  __shared__ float sred[8];
  const int tok = blockIdx.x;
  const int t = threadIdx.x;
  const float4 v = ((const float4*)(x + (size_t)tok * 1024))[t];
  float s  = v.x + v.y + v.z + v.w;
  float ss = v.x * v.x + v.y * v.y + v.z * v.z + v.w * v.w;
  #pragma unroll
  for (int o = 32; o > 0; o >>= 1) {
    s  += __shfl_xor(s, o);
    ss += __shfl_xor(ss, o);
  }
  const int w = t >> 6;
  if ((t & 63) == 0) { sred[w] = s; sred[4 + w] = ss; }
  __syncthreads();
  s  = sred[0] + sred[1] + sred[2] + sred[3];
  ss = sred[4] + sred[5] + sred[6] + sred[7];
  const float mu = s * (1.0f / 1024.0f);
  const float var = ss * (1.0f / 1024.0f) - mu * mu;
  const float rs = rsqrtf(var + 1e-5f);
  const float4 gg = ((const float4*)g)[t];
  const float4 b4 = ((const float4*)bb)[t];
  u16* o = xn + (size_t)tok * 1024 + t * 4;
  o[0] = f2bf((v.x - mu) * rs * gg.x + b4.x);
  o[1] = f2bf((v.y - mu) * rs * gg.y + b4.y);
  o[2] = f2bf((v.z - mu) * rs * gg.z + b4.z);
  o[3] = f2bf((v.w - mu) * rs * gg.w + b4.w);
}

// ---------------- host ----------------
extern "C" void kernel_launch(void* const* d_in, const int* in_sizes, int n_in,
                              void* d_out, int out_size, void* d_ws, size_t ws_size,
                              hipStream_t stream) {
  const int*   idx     = (const int*)  d_in[0];
  const float* tok_emb = (const float*)d_in[1];
  const float* pos_emb = (const float*)d_in[2];
  const float* wqkv    = (const float*)d_in[3];
  const float* bqkv    = (const float*)d_in[4];
  const float* wo      = (const float*)d_in[5];
  const float* bo      = (const float*)d_in[6];
  const float* w1      = (const float*)d_in[7];
  const float* b1      = (const float*)d_in[8];
  const float* w2      = (const float*)d_in[9];
  const float* b2      = (const float*)d_in[10];
  const float* ln_g    = (const float*)d_in[11];
  const float* ln_b    = (const float*)d_in[12];
  const float* out_w   = (const float*)d_in[13];
  const float* out_b   = (const float*)d_in[14];

  char* p = (char*)d_ws;
  auto take = [&](size_t n) { char* r = p; p += (n + 255) & ~(size_t)255; return r; };
  u16*   wqkv_t = (u16*)  take((size_t)1024 * 3072 * 2);
  u16*   wo_t   = (u16*)  take((size_t)1024 * 1024 * 2);
  u16*   w1_t   = (u16*)  take((size_t)1024 * 4096 * 2);
  u16*   w2_t   = (u16*)  take((size_t)4096 * 1024 * 2);
  u16*   wout_t = (u16*)  take((size_t)1024 * 1024 * 2);
  float* xf     = (float*)take((size_t)MT * 1024 * 4);
  u16*   xb     = (u16*)  take((size_t)MT * 1024 * 2);
  u16*   yb     = (u16*)  take((size_t)MT * 1024 * 2);
  u16*   big    = (u16*)  take((size_t)MT * 4096 * 2);

  const dim3 tb(32, 8);
  embed_kernel<<<MT, 256, 0, stream>>>(idx, tok_emb, pos_emb, xf, xb);

  for (int l = 0; l < 12; ++l) {
    transpose_cvt<<<dim3(3072 / 32, 1024 / 32), tb, 0, stream>>>(
        wqkv + (size_t)l * 1024 * 3072, wqkv_t, 1024, 3072);
    transpose_cvt<<<dim3(1024 / 32, 1024 / 32), tb, 0, stream>>>(
        wo + (size_t)l * 1024 * 1024, wo_t, 1024, 1024);
    transpose_cvt<<<dim3(4096 / 32, 1024 / 32), tb, 0, stream>>>(
        w1 + (size_t)l * 1024 * 4096, w1_t, 1024, 4096);
    transpose_cvt<<<dim3(1024 / 32, 4096 / 32), tb, 0, stream>>>(
        w2 + (size_t)l * 4096 * 1024, w2_t, 4096, 1024);

    gemm256p<0><<<(MT / 256) * (3072 / 256), 512, 0, stream>>>(
        xb, wqkv_t, bqkv + (size_t)l * 3072,
        nullptr, big, nullptr, MT, 3072, 1024, 3072 / 256);
    attn_kernel<<<dim3(16, 256), 256, 0, stream>>>(big, yb);
    gemm256p<2><<<(MT / 256) * (1024 / 256), 512, 0, stream>>>(
        yb, wo_t, bo + (size_t)l * 1024,
        xf, xb, nullptr, MT, 1024, 1024, 1024 / 256);
    gemm256p<1><<<(MT / 256) * (4096 / 256), 512, 0, stream>>>(
        xb, w1_t, b1 + (size_t)l * 4096,
        nullptr, big, nullptr, MT, 4096, 1024, 4096 / 256);
    gemm256p<2><<<(MT / 256) * (1024 / 256), 512, 0, stream>>>(
        big, w2_t, b2 + (size_t)l * 1024,
        xf, xb, nullptr, MT, 1024, 4096, 1024 / 256);
  }

  transpose_cvt<<<dim3(1024 / 32, 1024 / 32), tb, 0, stream>>>(out_w, wout_t, 1024, 1024);
  ln_kernel<<<MT, 256, 0, stream>>>(xf, ln_g, ln_b, yb);
  gemm256p<3><<<(MT / 256) * (1024 / 256), 512, 0, stream>>>(
      yb, wout_t, out_b, nullptr, nullptr, (float*)d_out, MT, 1024, 1024, 1024 / 256);
}

// Round 7
// 7060.645 us; speedup vs baseline: 1.0569x; 1.0284x over previous
//
#include <hip/hip_runtime.h>
#include <stdint.h>

typedef unsigned short u16;
typedef __bf16 bf16x8 __attribute__((ext_vector_type(8)));
typedef float f32x4 __attribute__((ext_vector_type(4)));

#define MT 16384   // BATCH*SEQ tokens

__device__ __forceinline__ u16 f2bf(float f) {
  union { float f; unsigned u; } x; x.f = f;
  unsigned r = x.u + 0x7fffu + ((x.u >> 16) & 1u);   // RNE
  return (u16)(r >> 16);
}

#pragma clang diagnostic push
#pragma clang diagnostic ignored "-Waddress-space-conversion"
typedef __attribute__((address_space(1))) unsigned as1u;
typedef __attribute__((address_space(3))) unsigned as3u;
// async global->LDS, 16B per lane; lbase must be wave-uniform (HW adds lane*16)
__device__ __forceinline__ void stage16(const u16* g, const u16* lbase) {
  __builtin_amdgcn_global_load_lds((as1u*)g, (as3u*)lbase, 16, 0, 0);
}
#pragma clang diagnostic pop

// ---------------- weight transpose + f32->bf16 convert ----------------
__global__ void __launch_bounds__(256)
transpose_cvt(const float* __restrict__ in, u16* __restrict__ out, int K, int N) {
  __shared__ float tile[32][33];
  const int k0 = blockIdx.y * 32, n0 = blockIdx.x * 32;
  const int tx = threadIdx.x, ty = threadIdx.y;   // block (32,8)
  #pragma unroll
  for (int r = 0; r < 32; r += 8)
    tile[ty + r][tx] = in[(size_t)(k0 + ty + r) * N + n0 + tx];
  __syncthreads();
  #pragma unroll
  for (int r = 0; r < 32; r += 8)
    out[(size_t)(n0 + ty + r) * K + k0 + tx] = f2bf(tile[tx][ty + r]);
}

// ---------------- embedding: x = tok_emb[idx] + pos_emb ----------------
__global__ void __launch_bounds__(256)
embed_kernel(const int* __restrict__ idx, const float* __restrict__ tok,
             const float* __restrict__ pos, float* __restrict__ x,
             u16* __restrict__ xb) {
  const int tk = blockIdx.x;
  const int s = tk & 63;
  const int id = idx[tk];
  const int t = threadIdx.x;
  float4 a = ((const float4*)(tok + (size_t)id * 1024))[t];
  float4 p = ((const float4*)(pos + (size_t)s * 1024))[t];
  float4 r; r.x = a.x + p.x; r.y = a.y + p.y; r.z = a.z + p.z; r.w = a.w + p.w;
  ((float4*)(x + (size_t)tk * 1024))[t] = r;
  u16* o = xb + (size_t)tk * 1024 + t * 4;
  o[0] = f2bf(r.x); o[1] = f2bf(r.y); o[2] = f2bf(r.z); o[3] = f2bf(r.w);
}

// ------------- 256x256 phased GEMM: C = A[M][K](bf16) @ Bt[N][K]^T + bias -------------
// 8 waves (2Mx4N), BK=64, double-buffered 128KiB LDS, round-4's PROVEN 0-conflict
// layout: [buf][op][256 rows][64 k], physical granule = logical ^ (row&7), inverse
// permutation on global_load_lds SOURCE. Staging unit = one 64-row chunk per wave
// call (8/tile). 4 phases/tile, each {ds_read quadrant | issue 2 chunk stages |
// [vmcnt(2)] | s_barrier | lgkmcnt(0) | setprio1 16xMFMA setprio0 | s_barrier}.
// Issue order A0,A2 / B0,B1 / B2,B3 / A1,A3; vmcnt(2) ONLY at p0,p3 (T3+T4):
// each wait leaves exactly the 2 newest loads in flight; A-stream gets 4 phases
// (~1240cy) of latency cover. Never drains to 0 inside the loop.
// EPI 0: bf16 | 1: gelu->bf16 | 2: +res f32+bf16 | 3: f32
template<int EPI>
__global__ void __launch_bounds__(512, 1)
gemm256p(const u16* __restrict__ A, const u16* __restrict__ Bt,
         const float* __restrict__ bias, float* __restrict__ resf,
         u16* __restrict__ outb, float* __restrict__ outf,
         int M, int N, int K, int gn) {
  __shared__ __align__(16) u16 lds[2][2][16384];   // [buf][A|B][256*64]
  const int t = threadIdx.x;
  const int lane = t & 63, w = t >> 6;
  const int wr = w >> 2, wc = w & 3;
  const int fr = lane & 15, fg = lane >> 4;

  // XCD swizzle (grid %8==0) + tn-fastest decomposition for A-panel L2 reuse
  const int nwg = gridDim.x;
  const int bid = blockIdx.x;
  const int sw = (bid & 7) * (nwg >> 3) + (bid >> 3);
  const int tn = sw % gn, tm = sw / gn;
  const int m0 = tm * 256, n0 = tn * 256;

  // staging: chunk c = rows [c*64,+64); wave w stages rows [c*64+w*8,+8)
  // lane l -> row +(l>>3), physical granule l&7; SOURCE logical granule (l&7)^(l>>3)
  const int srow = w * 8 + (lane >> 3);
  const int sg = (lane & 7) ^ (lane >> 3);
  const u16* gA[4]; const u16* gB[4];
  #pragma unroll
  for (int c = 0; c < 4; ++c) {
    gA[c] = A  + (size_t)(m0 + c * 64 + srow) * K + sg * 8;
    gB[c] = Bt + (size_t)(n0 + c * 64 + srow) * K + sg * 8;
  }
  const int lofs = w * 512;   // (w*8 rows)*64

  f32x4 acc[8][4] = {};
  const int NT = K >> 6;

  auto SA = [&](int b, int c, int ko) { stage16(gA[c] + ko, &lds[b][0][lofs + c * 4096]); };
  auto SB = [&](int b, int c, int ko) { stage16(gB[c] + ko, &lds[b][1][lofs + c * 4096]); };
  auto LDA4 = [&](bf16x8* af, int mq, int h, int c) {
    #pragma unroll
    for (int m = 0; m < 4; ++m) {
      const int row = wr * 128 + mq * 64 + m * 16 + fr;
      const int g = (fg + h * 4) ^ (fr & 7);     // physical granule
      af[m] = *(const bf16x8*)&lds[c][0][row * 64 + g * 8];
    }
  };
  auto LDB4 = [&](bf16x8* bv, int h, int c) {
    #pragma unroll
    for (int n = 0; n < 4; ++n) {
      const int row = wc * 64 + n * 16 + fr;
      const int g = (fg + h * 4) ^ (fr & 7);
      bv[n] = *(const bf16x8*)&lds[c][1][row * 64 + g * 8];
    }
  };
  auto MFMA16 = [&](bf16x8* af, bf16x8* bv, int mq) {
    __builtin_amdgcn_s_setprio(1);
    #pragma unroll
    for (int m = 0; m < 4; ++m)
      #pragma unroll
      for (int n = 0; n < 4; ++n)
        acc[mq * 4 + m][n] =
            __builtin_amdgcn_mfma_f32_16x16x32_bf16(af[m], bv[n], acc[mq * 4 + m][n], 0, 0, 0);
    __builtin_amdgcn_s_setprio(0);
  };
  #define BARRIER() __builtin_amdgcn_s_barrier()
  #define LGKM0()  asm volatile("s_waitcnt lgkmcnt(0)" ::: "memory")
  #define VMCNT2() asm volatile("s_waitcnt vmcnt(2)" ::: "memory")
  #define VMCNT0() asm volatile("s_waitcnt vmcnt(0)" ::: "memory")

  // prologue: tile 0 -> buf 0; last two issues = A1,A3 (consumed at p1)
  SA(0, 0, 0); SA(0, 2, 0);
  SB(0, 0, 0); SB(0, 1, 0); SB(0, 2, 0); SB(0, 3, 0);
  SA(0, 1, 0); SA(0, 3, 0);
  VMCNT2();                      // publish {A0,A2,B0-3}; leave A1,A3 in flight
  BARRIER();

  int cur = 0;
  for (int u = 0; u < NT; ++u) {
    const int ko = (u + 1 < NT) ? (u + 1) << 6 : 0;  // wrap: uniform vmcnt stream
    const int nb = cur ^ 1;
    bf16x8 af[4], bv[4];
    { // p0: (kk0, m0-3); issue A0,A2(next)
      LDA4(af, 0, 0, cur); LDB4(bv, 0, cur);
      SA(nb, 0, ko); SA(nb, 2, ko);
      VMCNT2();                  // publish A1,A3 (this tile)
      BARRIER(); LGKM0();
      MFMA16(af, bv, 0);
      BARRIER();
    }
    { // p1: (kk0, m4-7); issue B0,B1(next)
      LDA4(af, 1, 0, cur);
      SB(nb, 0, ko); SB(nb, 1, ko);
      BARRIER(); LGKM0();
      MFMA16(af, bv, 1);
      BARRIER();
    }
    { // p2: (kk1, m0-3); issue B2,B3(next)
      LDA4(af, 0, 1, cur); LDB4(bv, 1, cur);
      SB(nb, 2, ko); SB(nb, 3, ko);
      BARRIER(); LGKM0();
      MFMA16(af, bv, 0);
      BARRIER();
    }
    { // p3: (kk1, m4-7); issue A1,A3(next)
      LDA4(af, 1, 1, cur);
      SA(nb, 1, ko); SA(nb, 3, ko);
      VMCNT2();                  // publish next tile's {A0,A2,B0-3}
      BARRIER(); LGKM0();
      MFMA16(af, bv, 1);
      BARRIER();
    }
    cur = nb;
  }
  VMCNT0();                      // drain stage writes before LDS dealloc
  #undef BARRIER
  #undef LGKM0
  #undef VMCNT2
  #undef VMCNT0

  #pragma unroll
  for (int m = 0; m < 8; ++m) {
    const int row = m0 + wr * 128 + m * 16 + fg * 4;
    #pragma unroll
    for (int n = 0; n < 4; ++n) {
      const int col = n0 + wc * 64 + n * 16 + fr;
      const float bc = bias[col];
      #pragma unroll
      for (int i = 0; i < 4; ++i) {
        const size_t off = (size_t)(row + i) * N + col;
        float v = acc[m][n][i] + bc;
        if constexpr (EPI == 0) {
          outb[off] = f2bf(v);
        } else if constexpr (EPI == 1) {
          v = 0.5f * v * (1.0f + erff(v * 0.70710678118654752f));
          outb[off] = f2bf(v);
        } else if constexpr (EPI == 2) {
          v += resf[off];
          resf[off] = v;
          outb[off] = f2bf(v);
        } else {
          outf[off] = v;
        }
      }
    }
  }
}

// ---------------- attention (one block per (b,h)) ----------------
__global__ void __launch_bounds__(256)
attn_kernel(const u16* __restrict__ qkv, u16* __restrict__ y) {
  __shared__ __align__(16) u16 qs[64][72];    // Q; reused as P (bf16)
  __shared__ __align__(16) u16 ks[64][72];
  __shared__ __align__(16) u16 vts[64][72];   // V transposed: [dh][key]
  __shared__ __align__(16) float S[64][68];   // [query][key] f32
  __shared__ float red[4][64];

  const int h = blockIdx.x, b = blockIdx.y;
  const int t = threadIdx.x;
  const int lane = t & 63, w = t >> 6;
  const int fr = lane & 15, fg = lane >> 4;

  #pragma unroll
  for (int it = 0; it < 2; ++it) {
    const int id = t + it * 256;           // 0..511
    const int row = id >> 3, seg = id & 7;
    const size_t gq = (size_t)(b * 64 + row) * 3072 + h * 64 + seg * 8;
    *(uint4*)&qs[row][seg * 8] = *(const uint4*)&qkv[gq];
    *(uint4*)&ks[row][seg * 8] = *(const uint4*)&qkv[gq + 1024];
  }
  {
    const int d = t & 63;
    #pragma unroll
    for (int it = 0; it < 16; ++it) {
      const int s = (t >> 6) + it * 4;
      vts[d][s] = qkv[(size_t)(b * 64 + s) * 3072 + 2048 + h * 64 + d];
    }
  }
  __syncthreads();

  f32x4 sa[4] = {};
  #pragma unroll
  for (int kk = 0; kk < 64; kk += 32) {
    bf16x8 qa = *(const bf16x8*)&qs[w * 16 + fr][kk + fg * 8];
    #pragma unroll
    for (int n = 0; n < 4; ++n) {
      bf16x8 kb = *(const bf16x8*)&ks[n * 16 + fr][kk + fg * 8];
      sa[n] = __builtin_amdgcn_mfma_f32_16x16x32_bf16(qa, kb, sa[n], 0, 0, 0);
    }
  }
  #pragma unroll
  for (int n = 0; n < 4; ++n)
    #pragma unroll
    for (int i = 0; i < 4; ++i) {
      const int row = w * 16 + fg * 4 + i, col = n * 16 + fr;
      S[row][col] = (row >= col) ? sa[n][i] * 0.03125f : -1e30f;
    }
  __syncthreads();

  const int c = t & 63, q4 = t >> 6;
  float mx = -1e30f;
  float e[16];
  #pragma unroll
  for (int i = 0; i < 16; ++i) mx = fmaxf(mx, S[q4 * 16 + i][c]);
  red[q4][c] = mx;
  __syncthreads();
  mx = fmaxf(fmaxf(red[0][c], red[1][c]), fmaxf(red[2][c], red[3][c]));
  float sum = 0.f;
  #pragma unroll
  for (int i = 0; i < 16; ++i) { e[i] = __expf(S[q4 * 16 + i][c] - mx); sum += e[i]; }
  __syncthreads();
  red[q4][c] = sum;
  __syncthreads();
  sum = red[0][c] + red[1][c] + red[2][c] + red[3][c];
  const float inv = 1.0f / sum;
  u16 (*P)[72] = qs;
  #pragma unroll
  for (int i = 0; i < 16; ++i)
    P[q4 * 16 + i][c] = f2bf(e[i] * inv);
  __syncthreads();

  f32x4 oa[4] = {};
  #pragma unroll
  for (int kk = 0; kk < 64; kk += 32) {
    bf16x8 pa = *(const bf16x8*)&P[w * 16 + fr][kk + fg * 8];
    #pragma unroll
    for (int n = 0; n < 4; ++n) {
      bf16x8 vb = *(const bf16x8*)&vts[n * 16 + fr][kk + fg * 8];
      oa[n] = __builtin_amdgcn_mfma_f32_16x16x32_bf16(pa, vb, oa[n], 0, 0, 0);
    }
  }
  #pragma unroll
  for (int n = 0; n < 4; ++n)
    #pragma unroll
    for (int i = 0; i < 4; ++i) {
      const int row = w * 16 + fg * 4 + i, col = n * 16 + fr;
      y[(size_t)(b * 64 + row) * 1024 + h * 64 + col] = f2bf(oa[n][i]);
    }
}

// ---------------- final LayerNorm ----------------
__global__ void __launch_bounds__(256)
ln_kernel(const float* __restrict__ x, const float* __restrict__ g,
          const float* __restrict__ bb, u16* __restrict__ xn) {
  __shared__ float sred[8];
  const int tok = blockIdx.x;
  const int t = threadIdx.x;
  const float4 v = ((const float4*)(x + (size_t)tok * 1024))[t];
  float s  = v.x + v.y + v.z + v.w;
  float ss = v.x * v.x + v.y * v.y + v.z * v.z + v.w * v.w;
  #pragma unroll
  for (int o = 32; o > 0; o >>= 1) {
    s  += __shfl_xor(s, o);
    ss += __shfl_xor(ss, o);
  }
  const int w = t >> 6;
  if ((t & 63) == 0) { sred[w] = s; sred[4 + w] = ss; }
  __syncthreads();
  s  = sred[0] + sred[1] + sred[2] + sred[3];
  ss = sred[4] + sred[5] + sred[6] + sred[7];
  const float mu = s * (1.0f / 1024.0f);
  const float var = ss * (1.0f / 1024.0f) - mu * mu;
  const float rs = rsqrtf(var + 1e-5f);
  const float4 gg = ((const float4*)g)[t];
  const float4 b4 = ((const float4*)bb)[t];
  u16* o = xn + (size_t)tok * 1024 + t * 4;
  o[0] = f2bf((v.x - mu) * rs * gg.x + b4.x);
  o[1] = f2bf((v.y - mu) * rs * gg.y + b4.y);
  o[2] = f2bf((v.z - mu) * rs * gg.z + b4.z);
  o[3] = f2bf((v.w - mu) * rs * gg.w + b4.w);
}

// ---------------- host ----------------
extern "C" void kernel_launch(void* const* d_in, const int* in_sizes, int n_in,
                              void* d_out, int out_size, void* d_ws, size_t ws_size,
                              hipStream_t stream) {
  const int*   idx     = (const int*)  d_in[0];
  const float* tok_emb = (const float*)d_in[1];
  const float* pos_emb = (const float*)d_in[2];
  const float* wqkv    = (const float*)d_in[3];
  const float* bqkv    = (const float*)d_in[4];
  const float* wo      = (const float*)d_in[5];
  const float* bo      = (const float*)d_in[6];
  const float* w1      = (const float*)d_in[7];
  const float* b1      = (const float*)d_in[8];
  const float* w2      = (const float*)d_in[9];
  const float* b2      = (const float*)d_in[10];
  const float* ln_g    = (const float*)d_in[11];
  const float* ln_b    = (const float*)d_in[12];
  const float* out_w   = (const float*)d_in[13];
  const float* out_b   = (const float*)d_in[14];

  char* p = (char*)d_ws;
  auto take = [&](size_t n) { char* r = p; p += (n + 255) & ~(size_t)255; return r; };
  u16*   wqkv_t = (u16*)  take((size_t)1024 * 3072 * 2);
  u16*   wo_t   = (u16*)  take((size_t)1024 * 1024 * 2);
  u16*   w1_t   = (u16*)  take((size_t)1024 * 4096 * 2);
  u16*   w2_t   = (u16*)  take((size_t)4096 * 1024 * 2);
  u16*   wout_t = (u16*)  take((size_t)1024 * 1024 * 2);
  float* xf     = (float*)take((size_t)MT * 1024 * 4);
  u16*   xb     = (u16*)  take((size_t)MT * 1024 * 2);
  u16*   yb     = (u16*)  take((size_t)MT * 1024 * 2);
  u16*   big    = (u16*)  take((size_t)MT * 4096 * 2);

  const dim3 tb(32, 8);
  embed_kernel<<<MT, 256, 0, stream>>>(idx, tok_emb, pos_emb, xf, xb);

  for (int l = 0; l < 12; ++l) {
    transpose_cvt<<<dim3(3072 / 32, 1024 / 32), tb, 0, stream>>>(
        wqkv + (size_t)l * 1024 * 3072, wqkv_t, 1024, 3072);
    transpose_cvt<<<dim3(1024 / 32, 1024 / 32), tb, 0, stream>>>(
        wo + (size_t)l * 1024 * 1024, wo_t, 1024, 1024);
    transpose_cvt<<<dim3(4096 / 32, 1024 / 32), tb, 0, stream>>>(
        w1 + (size_t)l * 1024 * 4096, w1_t, 1024, 4096);
    transpose_cvt<<<dim3(1024 / 32, 4096 / 32), tb, 0, stream>>>(
        w2 + (size_t)l * 4096 * 1024, w2_t, 4096, 1024);

    gemm256p<0><<<(MT / 256) * (3072 / 256), 512, 0, stream>>>(
        xb, wqkv_t, bqkv + (size_t)l * 3072,
        nullptr, big, nullptr, MT, 3072, 1024, 3072 / 256);
    attn_kernel<<<dim3(16, 256), 256, 0, stream>>>(big, yb);
    gemm256p<2><<<(MT / 256) * (1024 / 256), 512, 0, stream>>>(
        yb, wo_t, bo + (size_t)l * 1024,
        xf, xb, nullptr, MT, 1024, 1024, 1024 / 256);
    gemm256p<1><<<(MT / 256) * (4096 / 256), 512, 0, stream>>>(
        xb, w1_t, b1 + (size_t)l * 4096,
        nullptr, big, nullptr, MT, 4096, 1024, 4096 / 256);
    gemm256p<2><<<(MT / 256) * (1024 / 256), 512, 0, stream>>>(
        big, w2_t, b2 + (size_t)l * 1024,
        xf, xb, nullptr, MT, 1024, 4096, 1024 / 256);
  }

  transpose_cvt<<<dim3(1024 / 32, 1024 / 32), tb, 0, stream>>>(out_w, wout_t, 1024, 1024);
  ln_kernel<<<MT, 256, 0, stream>>>(xf, ln_g, ln_b, yb);
  gemm256p<3><<<(MT / 256) * (1024 / 256), 512, 0, stream>>>(
      yb, wout_t, out_b, nullptr, nullptr, (float*)d_out, MT, 1024, 1024, 1024 / 256);
}